// Round 1
// 1045.326 us; speedup vs baseline: 1.0675x; 1.0675x over previous
//
#include <hip/hip_runtime.h>

// ---------------------------------------------------------------------------
// Masker: 3-layer MLP trunk (fp16 MFMA, BN in epilogue kernels) +
// 1024-step gumbel-softmax scan.
//
//  * JAX partitionable threefry verified R3 (absmax 3.9e-3): bits[i] =
//    o0^o1 of threefry2x32(key, (0, i)); keys[s] = threefry2x32((0,42),(0,s)).
//  * Scan algebra: state kept in UNNORMALIZED p-space. Per step:
//      pn[e] = exp2( p[e]*aC + lg[e] ),  lg = -2*log2(t_s),  aC = C2F/S_prev
//  * R5 change: the scan (64 CUs busy, 192 idle, 318 us) is split into 4
//    stage launches; 192 companion blocks co-launched with each stage
//    generate the NEXT stage's noise groups on the idle CUs. Stream
//    serialization gives producer->consumer ordering (no flags, no races).
//    Standalone noise_kernel shrinks to a 40-group pregen. Noise pack
//    de-unioned (scratch-risk removal).
//    Schedule (groups): pregen [0,40) | s1 [0,40)->[40,104) |
//    s2 [40,104)->[104,200) | s3 [104,200)->[200,256) | s4 [200,256).
//    Production capacity 1.63x consumption rate -> producers stay ahead;
//    if not, the stage merely extends (graceful, still useful work).
// ---------------------------------------------------------------------------

typedef _Float16 half8 __attribute__((ext_vector_type(8)));
typedef float floatx4 __attribute__((ext_vector_type(4)));

#define TINYF 1.17549435e-38f
#define LN2F  0.69314718055994531f
#define C2F   2.8853900817779268f   // 2*log2(e)
#define TSCALE 512.0f               // noise pre-scale (cancels in softmax)
#define TS_MIN 6.11e-5f             // just above fp16 min normal

#define COMBINE(o0, o1) ((o0) ^ (o1))

#if __has_builtin(__builtin_amdgcn_exp2f)
#define EXP2F(x) __builtin_amdgcn_exp2f(x)
#else
#define EXP2F(x) exp2f(x)
#endif
#if __has_builtin(__builtin_amdgcn_logf)
#define LOG2F(x) __builtin_amdgcn_logf(x)
#else
#define LOG2F(x) __log2f(x)
#endif
#if __has_builtin(__builtin_amdgcn_rcpf)
#define RCPF(x) __builtin_amdgcn_rcpf(x)
#else
#define RCPF(x) (1.0f/(x))
#endif

// ---------------- threefry2x32 (20 rounds), bit-exact vs JAX ----------------
__device__ __forceinline__ unsigned rotl32(unsigned x, int r) {
  return (x << r) | (x >> (32 - r));
}

__device__ __forceinline__ void tf2x32(unsigned k0, unsigned k1,
                                       unsigned x0, unsigned x1,
                                       unsigned &o0, unsigned &o1) {
  unsigned kx = k0 ^ k1 ^ 0x1BD11BDAu;
#define TFR(r) { x0 += x1; x1 = rotl32(x1, (r)); x1 ^= x0; }
  x0 += k0; x1 += k1;
  TFR(13) TFR(15) TFR(26) TFR(6)
  x0 += k1; x1 += kx + 1u;
  TFR(17) TFR(29) TFR(16) TFR(24)
  x0 += kx; x1 += k0 + 2u;
  TFR(13) TFR(15) TFR(26) TFR(6)
  x0 += k0; x1 += k1 + 3u;
  TFR(17) TFR(29) TFR(16) TFR(24)
  x0 += k1; x1 += kx + 4u;
  TFR(13) TFR(15) TFR(26) TFR(6)
  x0 += kx; x1 += k0 + 5u;
#undef TFR
  o0 = x0; o1 = x1;
}

// bits -> u (JAX uniform[tiny,1)) -> t = -ln(u), clamped >= 1e-7
__device__ __forceinline__ float bits_to_t(unsigned bits) {
  float f = __uint_as_float((bits >> 9) | 0x3f800000u) - 1.0f;
  float u = fmaxf(TINYF, f + TINYF);
  return fmaxf(-LN2F * LOG2F(u), 1.0e-7f);
}

// DPP butterfly wave64 sum; result broadcast via readlane(63) -> SGPR
__device__ __forceinline__ float wave_sum64(float x) {
  x += __int_as_float(__builtin_amdgcn_update_dpp(0, __float_as_int(x), 0xB1, 0xF, 0xF, true));   // quad_perm 1,0,3,2
  x += __int_as_float(__builtin_amdgcn_update_dpp(0, __float_as_int(x), 0x4E, 0xF, 0xF, true));   // quad_perm 2,3,0,1
  x += __int_as_float(__builtin_amdgcn_update_dpp(0, __float_as_int(x), 0x141, 0xF, 0xF, true));  // row_half_mirror
  x += __int_as_float(__builtin_amdgcn_update_dpp(0, __float_as_int(x), 0x140, 0xF, 0xF, true));  // row_mirror
  x += __int_as_float(__builtin_amdgcn_update_dpp(0, __float_as_int(x), 0x142, 0xA, 0xF, true));  // row_bcast15 -> rows 1,3
  x += __int_as_float(__builtin_amdgcn_update_dpp(0, __float_as_int(x), 0x143, 0xC, 0xF, true));  // row_bcast31 -> rows 2,3
  return __int_as_float(__builtin_amdgcn_readlane(__float_as_int(x), 63));
}

// keys[s] = fold_in(key(42), s) = threefry2x32((0,42), (0,s))
__global__ void keys_kernel(unsigned* __restrict__ keys) {
  int i = threadIdx.x;                 // 1024 threads, 1 block
  unsigned o0, o1;
  tf2x32(0u, 42u, 0u, (unsigned)i, o0, o1);
  keys[2*i] = o0; keys[2*i+1] = o1;
}

// f (fp32) -> fp16, 131072 elements
__global__ void cast_kernel(const float* __restrict__ f, _Float16* __restrict__ o) {
  int i = blockIdx.x * 256 + threadIdx.x;
  o[i] = (_Float16)f[i];
}

// ---------------- GEMM: P[kc][64][N] partial = A(64xK fp16) @ W(KxN fp32) ---
__global__ __launch_bounds__(256) void gemm_kernel(
    const _Float16* __restrict__ A, const float* __restrict__ W,
    float* __restrict__ P, int K, int N, int KC) {
  __shared__ _Float16 As[64 * 40];
  __shared__ _Float16 Ws[128 * 40];
  const int t = threadIdx.x;
  const int lane = t & 63, w = t >> 6;
  const int c0 = blockIdx.x * 128;
  const int k0beg = blockIdx.y * KC, k0end = k0beg + KC;

  floatx4 acc[4][2];
#pragma unroll
  for (int i = 0; i < 4; ++i)
#pragma unroll
    for (int j = 0; j < 2; ++j) acc[i][j] = (floatx4){0.f, 0.f, 0.f, 0.f};

  const int ar = t >> 2;
  const int ako = (t & 3) * 8;
  const int wn = (t & 31) * 4;
  const int wk = (t >> 5) * 2;

  uint4 av = *(const uint4*)(A + (size_t)ar * K + k0beg + ako);
  float4 wv[2][2];
#pragma unroll
  for (int kk = 0; kk < 2; ++kk) {
    int krow = k0beg + kk * 16 + wk;
    wv[kk][0] = *(const float4*)(W + (size_t)krow * N + c0 + wn);
    wv[kk][1] = *(const float4*)(W + (size_t)(krow + 1) * N + c0 + wn);
  }

  for (int k0 = k0beg; k0 < k0end; k0 += 32) {
    __syncthreads();
    *(uint4*)(&As[ar * 40 + ako]) = av;
#pragma unroll
    for (int kk = 0; kk < 2; ++kk) {
#pragma unroll
      for (int i = 0; i < 4; ++i) {
        const float* p0 = (const float*)&wv[kk][0];
        const float* p1 = (const float*)&wv[kk][1];
        _Float16 h0 = (_Float16)p0[i], h1 = (_Float16)p1[i];
        unsigned u = (unsigned)*(unsigned short*)&h0 |
                     ((unsigned)*(unsigned short*)&h1 << 16);
        *(unsigned*)(&Ws[(wn + i) * 40 + kk * 16 + wk]) = u;
      }
    }
    int kn = k0 + 32;
    if (kn < k0end) {
      av = *(const uint4*)(A + (size_t)ar * K + kn + ako);
#pragma unroll
      for (int kk = 0; kk < 2; ++kk) {
        int krow = kn + kk * 16 + wk;
        wv[kk][0] = *(const float4*)(W + (size_t)krow * N + c0 + wn);
        wv[kk][1] = *(const float4*)(W + (size_t)(krow + 1) * N + c0 + wn);
      }
    }
    __syncthreads();
    const int q = lane >> 4, ml = lane & 15;
    half8 bfrag[2];
#pragma unroll
    for (int nt = 0; nt < 2; ++nt)
      bfrag[nt] = *(const half8*)(&Ws[(w * 32 + nt * 16 + ml) * 40 + q * 8]);
#pragma unroll
    for (int mt = 0; mt < 4; ++mt) {
      half8 afrag = *(const half8*)(&As[(mt * 16 + ml) * 40 + q * 8]);
      acc[mt][0] = __builtin_amdgcn_mfma_f32_16x16x32_f16(afrag, bfrag[0], acc[mt][0], 0, 0, 0);
      acc[mt][1] = __builtin_amdgcn_mfma_f32_16x16x32_f16(afrag, bfrag[1], acc[mt][1], 0, 0, 0);
    }
  }
  const int q = lane >> 4, ml = lane & 15;
  float* Pb = P + (size_t)blockIdx.y * 64 * N;
#pragma unroll
  for (int mt = 0; mt < 4; ++mt)
#pragma unroll
    for (int nt = 0; nt < 2; ++nt)
#pragma unroll
      for (int i = 0; i < 4; ++i) {
        int m = mt * 16 + q * 4 + i;
        int n = c0 + w * 32 + nt * 16 + ml;
        Pb[(size_t)m * N + n] = acc[mt][nt][i];
      }
}

// ---------------- wide partial-sum reduce (for bn3's 16 K-chunks) -----------
__global__ __launch_bounds__(256) void reduce_kernel(
    const float* __restrict__ P, float* __restrict__ X, int nkc, int total) {
  int i = blockIdx.x * 256 + threadIdx.x;
  float s = 0.f;
  for (int kc = 0; kc < nkc; ++kc) s += P[(size_t)kc * total + i];
  X[i] = s;
}

// ---------------- BN epilogue ----------------------------------------------
__global__ __launch_bounds__(256) void bn_kernel(
    const float* __restrict__ P, int nkc, int N,
    const float* __restrict__ g, const float* __restrict__ be,
    _Float16* __restrict__ Hout, float* __restrict__ Fout, int mode) {
  int c = blockIdx.x * 256 + threadIdx.x;
  float x[64];
#pragma unroll
  for (int r = 0; r < 64; ++r) x[r] = 0.f;
  for (int kc = 0; kc < nkc; ++kc) {
    const float* Pb = P + (size_t)kc * 64 * N + c;
#pragma unroll
    for (int r = 0; r < 64; ++r) x[r] += Pb[(size_t)r * N];
  }
  float s = 0.f;
#pragma unroll
  for (int r = 0; r < 64; ++r) s += x[r];
  float mean = s * 0.015625f;
  float v = 0.f;
#pragma unroll
  for (int r = 0; r < 64; ++r) { float d = x[r] - mean; v += d * d; }
  v *= 0.015625f;
  float rs = rsqrtf(v + 1e-5f);
  if (mode == 0) {
    float gg = g[c], bb = be[c];
#pragma unroll
    for (int r = 0; r < 64; ++r) {
      float y = (x[r] - mean) * rs * gg + bb;
      Hout[(size_t)r * N + c] = (_Float16)fmaxf(y, 0.f);
    }
  } else {
#pragma unroll
    for (int r = 0; r < 64; ++r)
      Fout[(size_t)r * N + c] = (x[r] - mean) * rs;
  }
}

// ---------------- noise production: one group-row (r, sg), 256 threads ------
// bits(i = r*2048+c) = o0^o1 of tf2x32(keys[s], 0, i).  t_s = 512*(-ln u).
// layout noise[r][sg][t*8..][j]: 16-bit slot k = q*4+j inside the thread's
// 32-halfword record; 32-bit word w packs k=2w (lo) and k=2w+1 (hi).
// De-unioned: every index compile-time constant -> registers, no scratch.
__device__ __forceinline__ void produce_gr(
    const unsigned* __restrict__ keys, _Float16* __restrict__ noise,
    int r, int sg, int t) {
  unsigned k0[4], k1[4];
#pragma unroll
  for (int j = 0; j < 4; ++j) {
    k0[j] = keys[(sg * 4 + j) * 2];
    k1[j] = keys[(sg * 4 + j) * 2 + 1];
  }
  const unsigned bx1 = (unsigned)(r * 2048 + t * 8);
  uint4 out[4];
  unsigned* ow = (unsigned*)out;
#pragma unroll
  for (int w = 0; w < 16; ++w) {
    const int q = w >> 1;          // element sub-index 0..7
    const int j = (w & 1) * 2;     // step-column pair {j, j+1}
    unsigned o0, o1;
    tf2x32(k0[j], k1[j], 0u, bx1 + (unsigned)q, o0, o1);
    float ts0 = fmaxf(bits_to_t(COMBINE(o0, o1)) * TSCALE, TS_MIN);
    tf2x32(k0[j + 1], k1[j + 1], 0u, bx1 + (unsigned)q, o0, o1);
    float ts1 = fmaxf(bits_to_t(COMBINE(o0, o1)) * TSCALE, TS_MIN);
    _Float16 h0 = (_Float16)ts0, h1 = (_Float16)ts1;
    unsigned short u0, u1;
    __builtin_memcpy(&u0, &h0, 2);
    __builtin_memcpy(&u1, &h1, 2);
    ow[w] = (unsigned)u0 | ((unsigned)u1 << 16);
  }
  size_t base = (((size_t)r * 256 + sg) * 2048 + (size_t)t * 8) * 4;
  uint4* wp = (uint4*)(noise + base);
#pragma unroll
  for (int i = 0; i < 4; ++i) wp[i] = out[i];
}

// standalone pregen: blocks cover group-rows (bx&63 = r, bx>>6 = sg)
__global__ __launch_bounds__(256) void noise_kernel(
    const unsigned* __restrict__ keys, _Float16* __restrict__ noise) {
  const int bx = blockIdx.x;
  produce_gr(keys, noise, bx & 63, bx >> 6, threadIdx.x);
}

// ---------------- staged gumbel-softmax scan --------------------------------
// blocks 0..63: consumer (row = blockIdx.x), scans groups [gB,gE) from the
//   noise buffer (written by pregen or the PREVIOUS stage's companions —
//   stream serialization orders it, no flags needed).
// blocks 64..255: companions, produce groups [pB,pE) for the NEXT stage on
//   otherwise-idle CUs. [pB,pE) disjoint from [gB,gE).
// (gE-gB) must be EVEN (buffer-parity unrolled pairing).
__global__ __launch_bounds__(256) void stage_kernel(
    const float* __restrict__ mask0, _Float16* __restrict__ noise,
    const unsigned* __restrict__ keys, float* __restrict__ zout,
    float* __restrict__ PST, float* __restrict__ ZST, float* __restrict__ ACR,
    int gB, int gE, int pB, int pE) {
  __shared__ __align__(16) float partial[2][4];
  const int t = threadIdx.x;

  if (blockIdx.x >= 64) {            // ---- companion producer ----
    const int cid = blockIdx.x - 64; // 0..191
    for (int idx = pB * 64 + cid; idx < pE * 64; idx += 192)
      produce_gr(keys, noise, idx & 63, idx >> 6, t);
    return;
  }

  // ---- consumer: identical recurrence to the monolithic loop ----
  const int row = blockIdx.x;
  const int lane = t & 63, w = t >> 6;
  const bool first = (gB == 0), last = (gE == 256);

  float p[8], z[8];
  if (first) {
    union { float4 v[2]; float f[8]; } mm;
    mm.v[0] = *(const float4*)(mask0 + row * 2048 + t * 8);
    mm.v[1] = *(const float4*)(mask0 + row * 2048 + t * 8 + 4);
#pragma unroll
    for (int q = 0; q < 8; ++q) { p[q] = mm.f[q]; z[q] = 0.f; }
  } else {
    union { float4 v[2]; float f[8]; } mp, mz;
    mp.v[0] = *(const float4*)(PST + row * 2048 + t * 8);
    mp.v[1] = *(const float4*)(PST + row * 2048 + t * 8 + 4);
    mz.v[0] = *(const float4*)(ZST + row * 2048 + t * 8);
    mz.v[1] = *(const float4*)(ZST + row * 2048 + t * 8 + 4);
#pragma unroll
    for (int q = 0; q < 8; ++q) { p[q] = mp.f[q]; z[q] = mz.f[q]; }
  }
  float aC = first ? C2F : ACR[row];

  const _Float16* nbase = noise + (size_t)row * 2097152;  // 256 sg * 8192
  float lgA[8][4], lgB[8][4];
  uint4 nbufA[4], nbufB[4];

  auto prep8 = [&](float (&LN)[8][4], const uint4 (&nbC)[4], int j) {
#pragma unroll
    for (int q = 0; q < 8; ++q) {
      int h = q * 4 + j;
      unsigned d = ((const unsigned*)&nbC[h >> 3])[(h >> 1) & 3];
      unsigned short usv = (h & 1) ? (unsigned short)(d >> 16)
                                   : (unsigned short)(d & 0xffffu);
      _Float16 hv;
      __builtin_memcpy(&hv, &usv, 2);
      LN[q][j] = -2.0f * LOG2F((float)hv);
    }
  };

  {  // init: lgA <- group gB; nbufA <- group gB+1 data
    uint4 nbI[4];
    const uint4* p0 = (const uint4*)(nbase + (size_t)gB * 8192 + (size_t)t * 32);
    nbI[0] = p0[0]; nbI[1] = p0[1]; nbI[2] = p0[2]; nbI[3] = p0[3];
#pragma unroll
    for (int j = 0; j < 4; ++j) prep8(lgA, nbI, j);
    const uint4* p1 = (const uint4*)(nbase + (size_t)(gB + 1) * 8192 + (size_t)t * 32);
    nbufA[0] = p1[0]; nbufA[1] = p1[1]; nbufA[2] = p1[2]; nbufA[3] = p1[3];
  }

  // group sg: uses LC; consumes nbC (data sg+1) to build LN (lg of sg+1);
  // issues load of data sg+2 (clamped inside this stage's range) into nbL.
  auto run_group = [&](const float (&LC)[8][4], float (&LN)[8][4],
                       const uint4 (&nbC)[4], uint4 (&nbL)[4], int sg) {
    int gl = (sg + 2 < gE) ? sg + 2 : gE - 1;
    const uint4* pl = (const uint4*)(nbase + (size_t)gl * 8192 + (size_t)t * 32);
    nbL[0] = pl[0]; nbL[1] = pl[1]; nbL[2] = pl[2]; nbL[3] = pl[3];
#pragma unroll
    for (int j = 0; j < 4; ++j) {
      float pn[8];
#pragma unroll
      for (int q = 0; q < 8; ++q)
        pn[q] = EXP2F(fmaf(p[q], aC, LC[q][j]));
      float s = ((pn[0] + pn[1]) + (pn[2] + pn[3])) +
                ((pn[4] + pn[5]) + (pn[6] + pn[7]));
      s = wave_sum64(s);
      if (lane == 0) partial[j & 1][w] = s;
      __syncthreads();               // slot parity -> 1 barrier/step safe
      float4 ps = *(const float4*)(&partial[j & 1][0]);
      prep8(LN, nbC, j);             // scheduled into ds_read shadow
      float S = (ps.x + ps.y) + (ps.z + ps.w);
      float inv = RCPF(S);
      aC = inv * C2F;
#pragma unroll
      for (int q = 0; q < 8; ++q) {
        z[q] = fmaxf(z[q], pn[q] * inv);
        p[q] = pn[q];
      }
    }
  };

  for (int sg = gB; sg < gE; sg += 2) {
    run_group(lgA, lgB, nbufA, nbufB, sg);
    run_group(lgB, lgA, nbufB, nbufA, sg + 1);
  }

  if (last) {
    union { float4 v[2]; float f[8]; } oo;
#pragma unroll
    for (int q = 0; q < 8; ++q) oo.f[q] = z[q];
    *(float4*)(zout + row * 2048 + t * 8) = oo.v[0];
    *(float4*)(zout + row * 2048 + t * 8 + 4) = oo.v[1];
  } else {
    union { float4 v[2]; float f[8]; } op, oz;
#pragma unroll
    for (int q = 0; q < 8; ++q) { op.f[q] = p[q]; oz.f[q] = z[q]; }
    *(float4*)(PST + row * 2048 + t * 8) = op.v[0];
    *(float4*)(PST + row * 2048 + t * 8 + 4) = op.v[1];
    *(float4*)(ZST + row * 2048 + t * 8) = oz.v[0];
    *(float4*)(ZST + row * 2048 + t * 8 + 4) = oz.v[1];
    if (t == 0) ACR[row] = aC;
  }
}

// ---------------- legacy fallback (ws too small for noise buffer) -----------
__global__ __launch_bounds__(256) void loop_fallback_kernel(
    const float* __restrict__ mask0, const unsigned* __restrict__ keys,
    float* __restrict__ zout) {
  const int row = blockIdx.x;
  const int t = threadIdx.x;
  const int lane = t & 63, w = t >> 6;
  __shared__ __align__(16) float partial[2][4];
  __shared__ unsigned keysLds[2048];

  float m[8], z[8];
  {
    union { float4 v[2]; float f[8]; } mm;
    mm.v[0] = *(const float4*)(mask0 + row * 2048 + t * 8);
    mm.v[1] = *(const float4*)(mask0 + row * 2048 + t * 8 + 4);
#pragma unroll
    for (int q = 0; q < 8; ++q) { m[q] = mm.f[q]; z[q] = 0.f; }
  }
  for (int i = t; i < 2048; i += 256) keysLds[i] = keys[i];
  __syncthreads();
  const unsigned idx0 = (unsigned)(row * 2048 + t * 8);
  for (int sg = 0; sg < 256; ++sg) {
    float rg[8][4];
#pragma unroll
    for (int j = 0; j < 4; ++j) {
      unsigned kk0 = keysLds[(sg * 4 + j) * 2];
      unsigned kk1 = keysLds[(sg * 4 + j) * 2 + 1];
#pragma unroll
      for (int q = 0; q < 8; ++q) {
        unsigned o0, o1;
        tf2x32(kk0, kk1, 0u, idx0 + q, o0, o1);
        float tt = bits_to_t(COMBINE(o0, o1));
        rg[q][j] = RCPF(tt * tt);
      }
    }
#pragma unroll
    for (int j = 0; j < 4; ++j) {
      float pp[8], loc = 0.f;
#pragma unroll
      for (int q = 0; q < 8; ++q) {
        pp[q] = EXP2F(m[q] * C2F) * rg[q][j];
        loc += pp[q];
      }
      loc = wave_sum64(loc);
      if (lane == 0) partial[j & 1][w] = loc;
      __syncthreads();
      float4 ps = *(const float4*)(&partial[j & 1][0]);
      float S = (ps.x + ps.y) + (ps.z + ps.w);
      float inv = RCPF(S);
#pragma unroll
      for (int q = 0; q < 8; ++q) {
        m[q] = pp[q] * inv;
        z[q] = fmaxf(z[q], m[q]);
      }
    }
  }
  union { float4 v[2]; float f[8]; } oo;
#pragma unroll
  for (int q = 0; q < 8; ++q) oo.f[q] = z[q];
  *(float4*)(zout + row * 2048 + t * 8) = oo.v[0];
  *(float4*)(zout + row * 2048 + t * 8 + 4) = oo.v[1];
}

// ---------------- launcher --------------------------------------------------
#define OFF_A0  65536u
#define OFF_H1  327680u
#define OFF_H2  1376256u
#define OFF_M0  2424832u
#define OFF_P   2949120u
#define OFF_XR  19726336u
#define OFF_PST 20971520u
#define OFF_ZST 21495808u
#define OFF_ACR 22020096u
#define OFF_NOISE 33554432ull
#define NEED_PRE (33554432ull + 268435456ull)

extern "C" void kernel_launch(void* const* d_in, const int* in_sizes, int n_in,
                              void* d_out, int out_size, void* d_ws, size_t ws_size,
                              hipStream_t stream) {
  const float* f   = (const float*)d_in[0];
  const float* W1  = (const float*)d_in[1];
  const float* g1  = (const float*)d_in[3];
  const float* be1 = (const float*)d_in[4];
  const float* W2  = (const float*)d_in[5];
  const float* g2  = (const float*)d_in[7];
  const float* be2 = (const float*)d_in[8];
  const float* W3  = (const float*)d_in[9];

  char* ws = (char*)d_ws;
  unsigned*  keys  = (unsigned*)(ws);
  _Float16*  A0    = (_Float16*)(ws + OFF_A0);
  _Float16*  H1    = (_Float16*)(ws + OFF_H1);
  _Float16*  H2    = (_Float16*)(ws + OFF_H2);
  float*     M0    = (float*)(ws + OFF_M0);
  float*     P     = (float*)(ws + OFF_P);
  float*     Xr    = (float*)(ws + OFF_XR);
  float*     PST   = (float*)(ws + OFF_PST);
  float*     ZST   = (float*)(ws + OFF_ZST);
  float*     ACR   = (float*)(ws + OFF_ACR);
  _Float16*  noise = (_Float16*)(ws + OFF_NOISE);
  float*     z     = (float*)d_out;
  bool pre = ws_size >= NEED_PRE;

  keys_kernel<<<1, 1024, 0, stream>>>(keys);
  cast_kernel<<<512, 256, 0, stream>>>(f, A0);
  gemm_kernel<<<dim3(64, 4), 256, 0, stream>>>(A0, W1, P, 2048, 8192, 512);
  bn_kernel<<<32, 256, 0, stream>>>(P, 4, 8192, g1, be1, H1, nullptr, 0);
  gemm_kernel<<<dim3(64, 4), 256, 0, stream>>>(H1, W2, P, 8192, 8192, 2048);
  bn_kernel<<<32, 256, 0, stream>>>(P, 4, 8192, g2, be2, H2, nullptr, 0);
  gemm_kernel<<<dim3(16, 16), 256, 0, stream>>>(H2, W3, P, 8192, 2048, 512);
  reduce_kernel<<<512, 256, 0, stream>>>(P, Xr, 16, 131072);
  bn_kernel<<<8, 256, 0, stream>>>(Xr, 1, 2048, nullptr, nullptr, nullptr, M0, 1);
  if (pre) {
    // pregen groups [0,40); stages hand production forward geometrically
    noise_kernel<<<40 * 64, 256, 0, stream>>>(keys, noise);
    stage_kernel<<<256, 256, 0, stream>>>(M0, noise, keys, z, PST, ZST, ACR,
                                          0, 40, 40, 104);
    stage_kernel<<<256, 256, 0, stream>>>(M0, noise, keys, z, PST, ZST, ACR,
                                          40, 104, 104, 200);
    stage_kernel<<<256, 256, 0, stream>>>(M0, noise, keys, z, PST, ZST, ACR,
                                          104, 200, 200, 256);
    stage_kernel<<<64, 256, 0, stream>>>(M0, noise, keys, z, PST, ZST, ACR,
                                         200, 256, 256, 256);
  } else {
    loop_fallback_kernel<<<64, 256, 0, stream>>>(M0, keys, z);
  }
}

// Round 2
// 1014.922 us; speedup vs baseline: 1.0995x; 1.0300x over previous
//
#include <hip/hip_runtime.h>

// ---------------------------------------------------------------------------
// Masker: 3-layer MLP trunk (fp16 MFMA, BN in epilogue kernels) +
// 1024-step gumbel-softmax scan.
//
//  * JAX partitionable threefry verified R3 (absmax 3.9e-3): bits[i] =
//    o0^o1 of threefry2x32(key, (0, i)); keys[s] = threefry2x32((0,42),(0,s)).
//  * Scan algebra: state kept in UNNORMALIZED p-space. Per step:
//      pn[e] = exp2( p[e]*aC + lg[e] ),  lg = -2*log2(t_s),  aC = C2F/S_prev
//  * R5: 4 stage launches; companion blocks co-launched with each stage
//    generate the NEXT stage's noise groups. Stream serialization gives
//    producer->consumer ordering (no flags, no races).
//  * R6: R5 counters showed stages producer-bound (158 us, VALUBusy 70%,
//    1 producer block/CU = 1 wave/SIMD can't hide threefry dep chains).
//    Now 576 producer blocks (2-3/CU, co-resident with consumers);
//    consumers protected by s_setprio(1) (latency-critical serial scan vs
//    VALU-hog background producers). Schedule rebalanced geometrically:
//    pregen [0,32) | s1 [0,32)->[32,84) | s2 [32,84)->[84,160) |
//    s3 [84,160)->[160,256) | s4 [160,256) consumer-only (64 blocks).
// ---------------------------------------------------------------------------

typedef _Float16 half8 __attribute__((ext_vector_type(8)));
typedef float floatx4 __attribute__((ext_vector_type(4)));

#define TINYF 1.17549435e-38f
#define LN2F  0.69314718055994531f
#define C2F   2.8853900817779268f   // 2*log2(e)
#define TSCALE 512.0f               // noise pre-scale (cancels in softmax)
#define TS_MIN 6.11e-5f             // just above fp16 min normal

#define COMBINE(o0, o1) ((o0) ^ (o1))

#if __has_builtin(__builtin_amdgcn_exp2f)
#define EXP2F(x) __builtin_amdgcn_exp2f(x)
#else
#define EXP2F(x) exp2f(x)
#endif
#if __has_builtin(__builtin_amdgcn_logf)
#define LOG2F(x) __builtin_amdgcn_logf(x)
#else
#define LOG2F(x) __log2f(x)
#endif
#if __has_builtin(__builtin_amdgcn_rcpf)
#define RCPF(x) __builtin_amdgcn_rcpf(x)
#else
#define RCPF(x) (1.0f/(x))
#endif

// ---------------- threefry2x32 (20 rounds), bit-exact vs JAX ----------------
__device__ __forceinline__ unsigned rotl32(unsigned x, int r) {
  return (x << r) | (x >> (32 - r));
}

__device__ __forceinline__ void tf2x32(unsigned k0, unsigned k1,
                                       unsigned x0, unsigned x1,
                                       unsigned &o0, unsigned &o1) {
  unsigned kx = k0 ^ k1 ^ 0x1BD11BDAu;
#define TFR(r) { x0 += x1; x1 = rotl32(x1, (r)); x1 ^= x0; }
  x0 += k0; x1 += k1;
  TFR(13) TFR(15) TFR(26) TFR(6)
  x0 += k1; x1 += kx + 1u;
  TFR(17) TFR(29) TFR(16) TFR(24)
  x0 += kx; x1 += k0 + 2u;
  TFR(13) TFR(15) TFR(26) TFR(6)
  x0 += k0; x1 += k1 + 3u;
  TFR(17) TFR(29) TFR(16) TFR(24)
  x0 += k1; x1 += kx + 4u;
  TFR(13) TFR(15) TFR(26) TFR(6)
  x0 += kx; x1 += k0 + 5u;
#undef TFR
  o0 = x0; o1 = x1;
}

// bits -> u (JAX uniform[tiny,1)) -> t = -ln(u), clamped >= 1e-7
__device__ __forceinline__ float bits_to_t(unsigned bits) {
  float f = __uint_as_float((bits >> 9) | 0x3f800000u) - 1.0f;
  float u = fmaxf(TINYF, f + TINYF);
  return fmaxf(-LN2F * LOG2F(u), 1.0e-7f);
}

// DPP butterfly wave64 sum; result broadcast via readlane(63) -> SGPR
__device__ __forceinline__ float wave_sum64(float x) {
  x += __int_as_float(__builtin_amdgcn_update_dpp(0, __float_as_int(x), 0xB1, 0xF, 0xF, true));   // quad_perm 1,0,3,2
  x += __int_as_float(__builtin_amdgcn_update_dpp(0, __float_as_int(x), 0x4E, 0xF, 0xF, true));   // quad_perm 2,3,0,1
  x += __int_as_float(__builtin_amdgcn_update_dpp(0, __float_as_int(x), 0x141, 0xF, 0xF, true));  // row_half_mirror
  x += __int_as_float(__builtin_amdgcn_update_dpp(0, __float_as_int(x), 0x140, 0xF, 0xF, true));  // row_mirror
  x += __int_as_float(__builtin_amdgcn_update_dpp(0, __float_as_int(x), 0x142, 0xA, 0xF, true));  // row_bcast15 -> rows 1,3
  x += __int_as_float(__builtin_amdgcn_update_dpp(0, __float_as_int(x), 0x143, 0xC, 0xF, true));  // row_bcast31 -> rows 2,3
  return __int_as_float(__builtin_amdgcn_readlane(__float_as_int(x), 63));
}

// keys[s] = fold_in(key(42), s) = threefry2x32((0,42), (0,s))
__global__ void keys_kernel(unsigned* __restrict__ keys) {
  int i = threadIdx.x;                 // 1024 threads, 1 block
  unsigned o0, o1;
  tf2x32(0u, 42u, 0u, (unsigned)i, o0, o1);
  keys[2*i] = o0; keys[2*i+1] = o1;
}

// f (fp32) -> fp16, 131072 elements
__global__ void cast_kernel(const float* __restrict__ f, _Float16* __restrict__ o) {
  int i = blockIdx.x * 256 + threadIdx.x;
  o[i] = (_Float16)f[i];
}

// ---------------- GEMM: P[kc][64][N] partial = A(64xK fp16) @ W(KxN fp32) ---
__global__ __launch_bounds__(256) void gemm_kernel(
    const _Float16* __restrict__ A, const float* __restrict__ W,
    float* __restrict__ P, int K, int N, int KC) {
  __shared__ _Float16 As[64 * 40];
  __shared__ _Float16 Ws[128 * 40];
  const int t = threadIdx.x;
  const int lane = t & 63, w = t >> 6;
  const int c0 = blockIdx.x * 128;
  const int k0beg = blockIdx.y * KC, k0end = k0beg + KC;

  floatx4 acc[4][2];
#pragma unroll
  for (int i = 0; i < 4; ++i)
#pragma unroll
    for (int j = 0; j < 2; ++j) acc[i][j] = (floatx4){0.f, 0.f, 0.f, 0.f};

  const int ar = t >> 2;
  const int ako = (t & 3) * 8;
  const int wn = (t & 31) * 4;
  const int wk = (t >> 5) * 2;

  uint4 av = *(const uint4*)(A + (size_t)ar * K + k0beg + ako);
  float4 wv[2][2];
#pragma unroll
  for (int kk = 0; kk < 2; ++kk) {
    int krow = k0beg + kk * 16 + wk;
    wv[kk][0] = *(const float4*)(W + (size_t)krow * N + c0 + wn);
    wv[kk][1] = *(const float4*)(W + (size_t)(krow + 1) * N + c0 + wn);
  }

  for (int k0 = k0beg; k0 < k0end; k0 += 32) {
    __syncthreads();
    *(uint4*)(&As[ar * 40 + ako]) = av;
#pragma unroll
    for (int kk = 0; kk < 2; ++kk) {
#pragma unroll
      for (int i = 0; i < 4; ++i) {
        const float* p0 = (const float*)&wv[kk][0];
        const float* p1 = (const float*)&wv[kk][1];
        _Float16 h0 = (_Float16)p0[i], h1 = (_Float16)p1[i];
        unsigned u = (unsigned)*(unsigned short*)&h0 |
                     ((unsigned)*(unsigned short*)&h1 << 16);
        *(unsigned*)(&Ws[(wn + i) * 40 + kk * 16 + wk]) = u;
      }
    }
    int kn = k0 + 32;
    if (kn < k0end) {
      av = *(const uint4*)(A + (size_t)ar * K + kn + ako);
#pragma unroll
      for (int kk = 0; kk < 2; ++kk) {
        int krow = kn + kk * 16 + wk;
        wv[kk][0] = *(const float4*)(W + (size_t)krow * N + c0 + wn);
        wv[kk][1] = *(const float4*)(W + (size_t)(krow + 1) * N + c0 + wn);
      }
    }
    __syncthreads();
    const int q = lane >> 4, ml = lane & 15;
    half8 bfrag[2];
#pragma unroll
    for (int nt = 0; nt < 2; ++nt)
      bfrag[nt] = *(const half8*)(&Ws[(w * 32 + nt * 16 + ml) * 40 + q * 8]);
#pragma unroll
    for (int mt = 0; mt < 4; ++mt) {
      half8 afrag = *(const half8*)(&As[(mt * 16 + ml) * 40 + q * 8]);
      acc[mt][0] = __builtin_amdgcn_mfma_f32_16x16x32_f16(afrag, bfrag[0], acc[mt][0], 0, 0, 0);
      acc[mt][1] = __builtin_amdgcn_mfma_f32_16x16x32_f16(afrag, bfrag[1], acc[mt][1], 0, 0, 0);
    }
  }
  const int q = lane >> 4, ml = lane & 15;
  float* Pb = P + (size_t)blockIdx.y * 64 * N;
#pragma unroll
  for (int mt = 0; mt < 4; ++mt)
#pragma unroll
    for (int nt = 0; nt < 2; ++nt)
#pragma unroll
      for (int i = 0; i < 4; ++i) {
        int m = mt * 16 + q * 4 + i;
        int n = c0 + w * 32 + nt * 16 + ml;
        Pb[(size_t)m * N + n] = acc[mt][nt][i];
      }
}

// ---------------- wide partial-sum reduce (for bn3's 16 K-chunks) -----------
__global__ __launch_bounds__(256) void reduce_kernel(
    const float* __restrict__ P, float* __restrict__ X, int nkc, int total) {
  int i = blockIdx.x * 256 + threadIdx.x;
  float s = 0.f;
  for (int kc = 0; kc < nkc; ++kc) s += P[(size_t)kc * total + i];
  X[i] = s;
}

// ---------------- BN epilogue ----------------------------------------------
__global__ __launch_bounds__(256) void bn_kernel(
    const float* __restrict__ P, int nkc, int N,
    const float* __restrict__ g, const float* __restrict__ be,
    _Float16* __restrict__ Hout, float* __restrict__ Fout, int mode) {
  int c = blockIdx.x * 256 + threadIdx.x;
  float x[64];
#pragma unroll
  for (int r = 0; r < 64; ++r) x[r] = 0.f;
  for (int kc = 0; kc < nkc; ++kc) {
    const float* Pb = P + (size_t)kc * 64 * N + c;
#pragma unroll
    for (int r = 0; r < 64; ++r) x[r] += Pb[(size_t)r * N];
  }
  float s = 0.f;
#pragma unroll
  for (int r = 0; r < 64; ++r) s += x[r];
  float mean = s * 0.015625f;
  float v = 0.f;
#pragma unroll
  for (int r = 0; r < 64; ++r) { float d = x[r] - mean; v += d * d; }
  v *= 0.015625f;
  float rs = rsqrtf(v + 1e-5f);
  if (mode == 0) {
    float gg = g[c], bb = be[c];
#pragma unroll
    for (int r = 0; r < 64; ++r) {
      float y = (x[r] - mean) * rs * gg + bb;
      Hout[(size_t)r * N + c] = (_Float16)fmaxf(y, 0.f);
    }
  } else {
#pragma unroll
    for (int r = 0; r < 64; ++r)
      Fout[(size_t)r * N + c] = (x[r] - mean) * rs;
  }
}

// ---------------- noise production: one group-row (r, sg), 256 threads ------
// bits(i = r*2048+c) = o0^o1 of tf2x32(keys[s], 0, i).  t_s = 512*(-ln u).
// layout noise[r][sg][t*8..][j]: 16-bit slot k = q*4+j inside the thread's
// 32-halfword record; 32-bit word w packs k=2w (lo) and k=2w+1 (hi).
// De-unioned: every index compile-time constant -> registers, no scratch.
__device__ __forceinline__ void produce_gr(
    const unsigned* __restrict__ keys, _Float16* __restrict__ noise,
    int r, int sg, int t) {
  unsigned k0[4], k1[4];
#pragma unroll
  for (int j = 0; j < 4; ++j) {
    k0[j] = keys[(sg * 4 + j) * 2];
    k1[j] = keys[(sg * 4 + j) * 2 + 1];
  }
  const unsigned bx1 = (unsigned)(r * 2048 + t * 8);
  uint4 out[4];
  unsigned* ow = (unsigned*)out;
#pragma unroll
  for (int w = 0; w < 16; ++w) {
    const int q = w >> 1;          // element sub-index 0..7
    const int j = (w & 1) * 2;     // step-column pair {j, j+1}
    unsigned o0, o1;
    tf2x32(k0[j], k1[j], 0u, bx1 + (unsigned)q, o0, o1);
    float ts0 = fmaxf(bits_to_t(COMBINE(o0, o1)) * TSCALE, TS_MIN);
    tf2x32(k0[j + 1], k1[j + 1], 0u, bx1 + (unsigned)q, o0, o1);
    float ts1 = fmaxf(bits_to_t(COMBINE(o0, o1)) * TSCALE, TS_MIN);
    _Float16 h0 = (_Float16)ts0, h1 = (_Float16)ts1;
    unsigned short u0, u1;
    __builtin_memcpy(&u0, &h0, 2);
    __builtin_memcpy(&u1, &h1, 2);
    ow[w] = (unsigned)u0 | ((unsigned)u1 << 16);
  }
  size_t base = (((size_t)r * 256 + sg) * 2048 + (size_t)t * 8) * 4;
  uint4* wp = (uint4*)(noise + base);
#pragma unroll
  for (int i = 0; i < 4; ++i) wp[i] = out[i];
}

// standalone pregen: blocks cover group-rows (bx&63 = r, bx>>6 = sg)
__global__ __launch_bounds__(256) void noise_kernel(
    const unsigned* __restrict__ keys, _Float16* __restrict__ noise) {
  const int bx = blockIdx.x;
  produce_gr(keys, noise, bx & 63, bx >> 6, threadIdx.x);
}

// ---------------- staged gumbel-softmax scan --------------------------------
// blocks 0..63: consumer (row = blockIdx.x), scans groups [gB,gE) from the
//   noise buffer (written by pregen or the PREVIOUS stage's companions —
//   stream serialization orders it, no flags needed). s_setprio(1): the
//   serial scan chain is latency-critical; co-resident producer waves are
//   VALU hogs — priority keeps the scan's issue slots.
// blocks 64..: companions, produce groups [pB,pE) for the NEXT stage.
//   [pB,pE) disjoint from [gB,gE). (gE-gB) must be EVEN.
__global__ __launch_bounds__(256) void stage_kernel(
    const float* __restrict__ mask0, _Float16* __restrict__ noise,
    const unsigned* __restrict__ keys, float* __restrict__ zout,
    float* __restrict__ PST, float* __restrict__ ZST, float* __restrict__ ACR,
    int gB, int gE, int pB, int pE) {
  __shared__ __align__(16) float partial[2][4];
  const int t = threadIdx.x;

  if (blockIdx.x >= 64) {            // ---- companion producer ----
    const int cid = blockIdx.x - 64;
    const int nprod = gridDim.x - 64;
    for (int idx = pB * 64 + cid; idx < pE * 64; idx += nprod)
      produce_gr(keys, noise, idx & 63, idx >> 6, t);
    return;
  }

  // ---- consumer: identical recurrence to the monolithic loop ----
  __builtin_amdgcn_s_setprio(1);
  const int row = blockIdx.x;
  const int lane = t & 63, w = t >> 6;
  const bool first = (gB == 0), last = (gE == 256);

  float p[8], z[8];
  if (first) {
    union { float4 v[2]; float f[8]; } mm;
    mm.v[0] = *(const float4*)(mask0 + row * 2048 + t * 8);
    mm.v[1] = *(const float4*)(mask0 + row * 2048 + t * 8 + 4);
#pragma unroll
    for (int q = 0; q < 8; ++q) { p[q] = mm.f[q]; z[q] = 0.f; }
  } else {
    union { float4 v[2]; float f[8]; } mp, mz;
    mp.v[0] = *(const float4*)(PST + row * 2048 + t * 8);
    mp.v[1] = *(const float4*)(PST + row * 2048 + t * 8 + 4);
    mz.v[0] = *(const float4*)(ZST + row * 2048 + t * 8);
    mz.v[1] = *(const float4*)(ZST + row * 2048 + t * 8 + 4);
#pragma unroll
    for (int q = 0; q < 8; ++q) { p[q] = mp.f[q]; z[q] = mz.f[q]; }
  }
  float aC = first ? C2F : ACR[row];

  const _Float16* nbase = noise + (size_t)row * 2097152;  // 256 sg * 8192
  float lgA[8][4], lgB[8][4];
  uint4 nbufA[4], nbufB[4];

  auto prep8 = [&](float (&LN)[8][4], const uint4 (&nbC)[4], int j) {
#pragma unroll
    for (int q = 0; q < 8; ++q) {
      int h = q * 4 + j;
      unsigned d = ((const unsigned*)&nbC[h >> 3])[(h >> 1) & 3];
      unsigned short usv = (h & 1) ? (unsigned short)(d >> 16)
                                   : (unsigned short)(d & 0xffffu);
      _Float16 hv;
      __builtin_memcpy(&hv, &usv, 2);
      LN[q][j] = -2.0f * LOG2F((float)hv);
    }
  };

  {  // init: lgA <- group gB; nbufA <- group gB+1 data
    uint4 nbI[4];
    const uint4* p0 = (const uint4*)(nbase + (size_t)gB * 8192 + (size_t)t * 32);
    nbI[0] = p0[0]; nbI[1] = p0[1]; nbI[2] = p0[2]; nbI[3] = p0[3];
#pragma unroll
    for (int j = 0; j < 4; ++j) prep8(lgA, nbI, j);
    const uint4* p1 = (const uint4*)(nbase + (size_t)(gB + 1) * 8192 + (size_t)t * 32);
    nbufA[0] = p1[0]; nbufA[1] = p1[1]; nbufA[2] = p1[2]; nbufA[3] = p1[3];
  }

  // group sg: uses LC; consumes nbC (data sg+1) to build LN (lg of sg+1);
  // issues load of data sg+2 (clamped inside this stage's range) into nbL.
  auto run_group = [&](const float (&LC)[8][4], float (&LN)[8][4],
                       const uint4 (&nbC)[4], uint4 (&nbL)[4], int sg) {
    int gl = (sg + 2 < gE) ? sg + 2 : gE - 1;
    const uint4* pl = (const uint4*)(nbase + (size_t)gl * 8192 + (size_t)t * 32);
    nbL[0] = pl[0]; nbL[1] = pl[1]; nbL[2] = pl[2]; nbL[3] = pl[3];
#pragma unroll
    for (int j = 0; j < 4; ++j) {
      float pn[8];
#pragma unroll
      for (int q = 0; q < 8; ++q)
        pn[q] = EXP2F(fmaf(p[q], aC, LC[q][j]));
      float s = ((pn[0] + pn[1]) + (pn[2] + pn[3])) +
                ((pn[4] + pn[5]) + (pn[6] + pn[7]));
      s = wave_sum64(s);
      if (lane == 0) partial[j & 1][w] = s;
      __syncthreads();               // slot parity -> 1 barrier/step safe
      float4 ps = *(const float4*)(&partial[j & 1][0]);
      prep8(LN, nbC, j);             // scheduled into ds_read shadow
      float S = (ps.x + ps.y) + (ps.z + ps.w);
      float inv = RCPF(S);
      aC = inv * C2F;
#pragma unroll
      for (int q = 0; q < 8; ++q) {
        z[q] = fmaxf(z[q], pn[q] * inv);
        p[q] = pn[q];
      }
    }
  };

  for (int sg = gB; sg < gE; sg += 2) {
    run_group(lgA, lgB, nbufA, nbufB, sg);
    run_group(lgB, lgA, nbufB, nbufA, sg + 1);
  }

  if (last) {
    union { float4 v[2]; float f[8]; } oo;
#pragma unroll
    for (int q = 0; q < 8; ++q) oo.f[q] = z[q];
    *(float4*)(zout + row * 2048 + t * 8) = oo.v[0];
    *(float4*)(zout + row * 2048 + t * 8 + 4) = oo.v[1];
  } else {
    union { float4 v[2]; float f[8]; } op, oz;
#pragma unroll
    for (int q = 0; q < 8; ++q) { op.f[q] = p[q]; oz.f[q] = z[q]; }
    *(float4*)(PST + row * 2048 + t * 8) = op.v[0];
    *(float4*)(PST + row * 2048 + t * 8 + 4) = op.v[1];
    *(float4*)(ZST + row * 2048 + t * 8) = oz.v[0];
    *(float4*)(ZST + row * 2048 + t * 8 + 4) = oz.v[1];
    if (t == 0) ACR[row] = aC;
  }
  __builtin_amdgcn_s_setprio(0);
}

// ---------------- legacy fallback (ws too small for noise buffer) -----------
__global__ __launch_bounds__(256) void loop_fallback_kernel(
    const float* __restrict__ mask0, const unsigned* __restrict__ keys,
    float* __restrict__ zout) {
  const int row = blockIdx.x;
  const int t = threadIdx.x;
  const int lane = t & 63, w = t >> 6;
  __shared__ __align__(16) float partial[2][4];
  __shared__ unsigned keysLds[2048];

  float m[8], z[8];
  {
    union { float4 v[2]; float f[8]; } mm;
    mm.v[0] = *(const float4*)(mask0 + row * 2048 + t * 8);
    mm.v[1] = *(const float4*)(mask0 + row * 2048 + t * 8 + 4);
#pragma unroll
    for (int q = 0; q < 8; ++q) { m[q] = mm.f[q]; z[q] = 0.f; }
  }
  for (int i = t; i < 2048; i += 256) keysLds[i] = keys[i];
  __syncthreads();
  const unsigned idx0 = (unsigned)(row * 2048 + t * 8);
  for (int sg = 0; sg < 256; ++sg) {
    float rg[8][4];
#pragma unroll
    for (int j = 0; j < 4; ++j) {
      unsigned kk0 = keysLds[(sg * 4 + j) * 2];
      unsigned kk1 = keysLds[(sg * 4 + j) * 2 + 1];
#pragma unroll
      for (int q = 0; q < 8; ++q) {
        unsigned o0, o1;
        tf2x32(kk0, kk1, 0u, idx0 + q, o0, o1);
        float tt = bits_to_t(COMBINE(o0, o1));
        rg[q][j] = RCPF(tt * tt);
      }
    }
#pragma unroll
    for (int j = 0; j < 4; ++j) {
      float pp[8], loc = 0.f;
#pragma unroll
      for (int q = 0; q < 8; ++q) {
        pp[q] = EXP2F(m[q] * C2F) * rg[q][j];
        loc += pp[q];
      }
      loc = wave_sum64(loc);
      if (lane == 0) partial[j & 1][w] = loc;
      __syncthreads();
      float4 ps = *(const float4*)(&partial[j & 1][0]);
      float S = (ps.x + ps.y) + (ps.z + ps.w);
      float inv = RCPF(S);
#pragma unroll
      for (int q = 0; q < 8; ++q) {
        m[q] = pp[q] * inv;
        z[q] = fmaxf(z[q], m[q]);
      }
    }
  }
  union { float4 v[2]; float f[8]; } oo;
#pragma unroll
  for (int q = 0; q < 8; ++q) oo.f[q] = z[q];
  *(float4*)(zout + row * 2048 + t * 8) = oo.v[0];
  *(float4*)(zout + row * 2048 + t * 8 + 4) = oo.v[1];
}

// ---------------- launcher --------------------------------------------------
#define OFF_A0  65536u
#define OFF_H1  327680u
#define OFF_H2  1376256u
#define OFF_M0  2424832u
#define OFF_P   2949120u
#define OFF_XR  19726336u
#define OFF_PST 20971520u
#define OFF_ZST 21495808u
#define OFF_ACR 22020096u
#define OFF_NOISE 33554432ull
#define NEED_PRE (33554432ull + 268435456ull)

extern "C" void kernel_launch(void* const* d_in, const int* in_sizes, int n_in,
                              void* d_out, int out_size, void* d_ws, size_t ws_size,
                              hipStream_t stream) {
  const float* f   = (const float*)d_in[0];
  const float* W1  = (const float*)d_in[1];
  const float* g1  = (const float*)d_in[3];
  const float* be1 = (const float*)d_in[4];
  const float* W2  = (const float*)d_in[5];
  const float* g2  = (const float*)d_in[7];
  const float* be2 = (const float*)d_in[8];
  const float* W3  = (const float*)d_in[9];

  char* ws = (char*)d_ws;
  unsigned*  keys  = (unsigned*)(ws);
  _Float16*  A0    = (_Float16*)(ws + OFF_A0);
  _Float16*  H1    = (_Float16*)(ws + OFF_H1);
  _Float16*  H2    = (_Float16*)(ws + OFF_H2);
  float*     M0    = (float*)(ws + OFF_M0);
  float*     P     = (float*)(ws + OFF_P);
  float*     Xr    = (float*)(ws + OFF_XR);
  float*     PST   = (float*)(ws + OFF_PST);
  float*     ZST   = (float*)(ws + OFF_ZST);
  float*     ACR   = (float*)(ws + OFF_ACR);
  _Float16*  noise = (_Float16*)(ws + OFF_NOISE);
  float*     z     = (float*)d_out;
  bool pre = ws_size >= NEED_PRE;

  keys_kernel<<<1, 1024, 0, stream>>>(keys);
  cast_kernel<<<512, 256, 0, stream>>>(f, A0);
  gemm_kernel<<<dim3(64, 4), 256, 0, stream>>>(A0, W1, P, 2048, 8192, 512);
  bn_kernel<<<32, 256, 0, stream>>>(P, 4, 8192, g1, be1, H1, nullptr, 0);
  gemm_kernel<<<dim3(64, 4), 256, 0, stream>>>(H1, W2, P, 8192, 8192, 2048);
  bn_kernel<<<32, 256, 0, stream>>>(P, 4, 8192, g2, be2, H2, nullptr, 0);
  gemm_kernel<<<dim3(16, 16), 256, 0, stream>>>(H2, W3, P, 8192, 2048, 512);
  reduce_kernel<<<512, 256, 0, stream>>>(P, Xr, 16, 131072);
  bn_kernel<<<8, 256, 0, stream>>>(Xr, 1, 2048, nullptr, nullptr, nullptr, M0, 1);
  if (pre) {
    // pregen [0,32); stages hand production forward geometrically (ratio
    // sized for producer:consumer rate ~1.5 with 576 producer blocks)
    noise_kernel<<<32 * 64, 256, 0, stream>>>(keys, noise);
    stage_kernel<<<640, 256, 0, stream>>>(M0, noise, keys, z, PST, ZST, ACR,
                                          0, 32, 32, 84);
    stage_kernel<<<640, 256, 0, stream>>>(M0, noise, keys, z, PST, ZST, ACR,
                                          32, 84, 84, 160);
    stage_kernel<<<640, 256, 0, stream>>>(M0, noise, keys, z, PST, ZST, ACR,
                                          84, 160, 160, 256);
    stage_kernel<<<64, 256, 0, stream>>>(M0, noise, keys, z, PST, ZST, ACR,
                                         160, 256, 256, 256);
  } else {
    loop_fallback_kernel<<<64, 256, 0, stream>>>(M0, keys, z);
  }
}